// Round 1
// baseline (249.403 us; speedup 1.0000x reference)
//
#include <hip/hip_runtime.h>

// NCE loss: out0 = align + w*uniform, out1 = align, out2 = uniform
// align[n]   = logsig(ref[n]·pos[n]/T)
// uniform[n] = mean_m logsig(-ref[n]·neg[m]/T)
// N=M=8192, D=512, T=0.5, w=1.0

typedef __attribute__((ext_vector_type(8))) short short8;
typedef __attribute__((ext_vector_type(8))) unsigned short ushort8;
typedef __attribute__((ext_vector_type(4))) float f32x4;

constexpr int N_ = 8192;
constexpr int M_ = 8192;
constexpr int D_ = 512;
constexpr float INV_T = 2.0f;       // 1/0.5
constexpr float NEG_W = 1.0f;
constexpr float LOG2E = 1.4426950408889634f;
constexpr float LN2   = 0.6931471805599453f;

#define BM 128
#define BN 128
#define BK 64
#define NKT (D_ / BK)   // 8 K-tiles

__device__ __forceinline__ unsigned short f2bf(float f) {
  unsigned int u = __builtin_bit_cast(unsigned int, f);
  u += 0x7FFFu + ((u >> 16) & 1u);   // round-to-nearest-even
  return (unsigned short)(u >> 16);
}

__device__ __forceinline__ float logsig_neg(float s) {
  // log sigmoid(-s) = min(-s, 0) - log1p(exp(-|s|))
  float t = __builtin_fabsf(s);
  float e = __builtin_amdgcn_exp2f(-t * LOG2E);
  float l = __builtin_amdgcn_logf(1.0f + e) * LN2;
  return fminf(-s, 0.0f) - l;
}

__global__ __launch_bounds__(256) void nce_gemm(
    const float* __restrict__ A,   // ref  (N, D)
    const float* __restrict__ B,   // neg  (M, D)
    float* __restrict__ rowsum) {  // (N,) fp32, pre-zeroed
  __shared__ __align__(16) unsigned short As[BM * BK];
  __shared__ __align__(16) unsigned short Bs[BN * BK];

  const int tid  = threadIdx.x;
  const int lane = tid & 63;
  const int wid  = tid >> 6;
  const int wr   = wid >> 1;   // wave row 0..1
  const int wc   = wid & 1;    // wave col 0..1

  // XCD-aware swizzle (nwg = 4096, divisible by 8 -> bijective)
  const int nwg = gridDim.x;
  const int per = nwg >> 3;
  const int bid = blockIdx.x;
  const int swz = (bid & 7) * per + (bid >> 3);
  const int brow = (swz >> 6) * BM;   // 64 row-blocks
  const int bcol = (swz & 63) * BN;   // 64 col-blocks

  // staging geometry: 4 groups, each thread 8 elems/group per matrix
  const int r0 = tid >> 3;           // 0..31
  const int k0 = (tid & 7) * 8;      // 0..56
  const unsigned int wof0 =
      ((unsigned int)(r0 * 128 + k0 * 2)) ^ (((unsigned int)r0 & 7u) << 4);
  const float* pa = A + (size_t)(brow + r0) * D_ + k0;
  const float* pb = B + (size_t)(bcol + r0) * D_ + k0;

  f32x4 acc[4][4] = {};
  f32x4 ra[8], rb[8];

  auto ldglobal = [&](int kt) {
#pragma unroll
    for (int g = 0; g < 4; ++g) {
      const f32x4* sa =
          reinterpret_cast<const f32x4*>(pa + (size_t)g * 32 * D_ + kt * BK);
      ra[2 * g]     = sa[0];
      ra[2 * g + 1] = sa[1];
      const f32x4* sb =
          reinterpret_cast<const f32x4*>(pb + (size_t)g * 32 * D_ + kt * BK);
      rb[2 * g]     = sb[0];
      rb[2 * g + 1] = sb[1];
    }
  };
  auto stlds = [&]() {
#pragma unroll
    for (int g = 0; g < 4; ++g) {
      ushort8 va, vb;
#pragma unroll
      for (int i = 0; i < 4; ++i) {
        va[i]     = f2bf(ra[2 * g][i]);
        va[4 + i] = f2bf(ra[2 * g + 1][i]);
        vb[i]     = f2bf(rb[2 * g][i]);
        vb[4 + i] = f2bf(rb[2 * g + 1][i]);
      }
      *reinterpret_cast<ushort8*>(reinterpret_cast<char*>(As) +
                                  (wof0 + g * 4096u)) = va;
      *reinterpret_cast<ushort8*>(reinterpret_cast<char*>(Bs) +
                                  (wof0 + g * 4096u)) = vb;
    }
  };

  // prologue: stage tile 0
  ldglobal(0);
  stlds();
  __syncthreads();

  for (int kt = 0; kt < NKT; ++kt) {
    if (kt + 1 < NKT) ldglobal(kt + 1);  // prefetch next tile into regs

    // compute current tile from LDS
#pragma unroll
    for (int ks = 0; ks < 2; ++ks) {
      short8 af[4], bfr[4];
      const int kk = ks * 32 + (lane >> 4) * 8;
#pragma unroll
      for (int mf = 0; mf < 4; ++mf) {
        unsigned int row = wr * 64 + mf * 16 + (lane & 15);
        unsigned int off = (row * 128u + kk * 2u) ^ ((row & 7u) << 4);
        af[mf] = *reinterpret_cast<const short8*>(
            reinterpret_cast<const char*>(As) + off);
      }
#pragma unroll
      for (int nf = 0; nf < 4; ++nf) {
        unsigned int row = wc * 64 + nf * 16 + (lane & 15);
        unsigned int off = (row * 128u + kk * 2u) ^ ((row & 7u) << 4);
        bfr[nf] = *reinterpret_cast<const short8*>(
            reinterpret_cast<const char*>(Bs) + off);
      }
#pragma unroll
      for (int mf = 0; mf < 4; ++mf)
#pragma unroll
        for (int nf = 0; nf < 4; ++nf)
          acc[mf][nf] = __builtin_amdgcn_mfma_f32_16x16x32_bf16(
              af[mf], bfr[nf], acc[mf][nf], 0, 0, 0);
    }
    __syncthreads();
    if (kt + 1 < NKT) stlds();  // write prefetched tile
    __syncthreads();
  }

  // epilogue: uni = logsig(-s), reduce over the 128 cols of this tile
  float part[16];
#pragma unroll
  for (int mf = 0; mf < 4; ++mf)
#pragma unroll
    for (int r = 0; r < 4; ++r) {
      float ssum = 0.0f;
#pragma unroll
      for (int nf = 0; nf < 4; ++nf) {
        float s = acc[mf][nf][r] * INV_T;
        ssum += logsig_neg(s);
      }
      part[mf * 4 + r] = ssum;
    }
  // sum across the 16 lanes holding the same row (cols 0..15 of fragment)
#pragma unroll
  for (int i = 0; i < 16; ++i) {
    float v = part[i];
    v += __shfl_xor(v, 1);
    v += __shfl_xor(v, 2);
    v += __shfl_xor(v, 4);
    v += __shfl_xor(v, 8);
    part[i] = v;
  }
  if ((lane & 15) == 0) {
    const int g = lane >> 4;  // row sub-group 0..3
#pragma unroll
    for (int mf = 0; mf < 4; ++mf)
#pragma unroll
      for (int r = 0; r < 4; ++r)
        atomicAdd(&rowsum[brow + wr * 64 + mf * 16 + g * 4 + r],
                  part[mf * 4 + r]);
  }
}

__global__ __launch_bounds__(256) void nce_combine(
    const float* __restrict__ ref, const float* __restrict__ pos,
    const float* __restrict__ rowsum, float* __restrict__ out) {
  const int wid  = threadIdx.x >> 6;
  const int lane = threadIdx.x & 63;
  const int n    = blockIdx.x * 4 + wid;

  const f32x4* pr =
      reinterpret_cast<const f32x4*>(ref + (size_t)n * D_ + lane * 8);
  const f32x4* pp =
      reinterpret_cast<const f32x4*>(pos + (size_t)n * D_ + lane * 8);
  f32x4 a0 = pr[0], a1 = pr[1], b0 = pp[0], b1 = pp[1];
  float d = 0.0f;
#pragma unroll
  for (int i = 0; i < 4; ++i) d = __builtin_fmaf(a0[i], b0[i], d);
#pragma unroll
  for (int i = 0; i < 4; ++i) d = __builtin_fmaf(a1[i], b1[i], d);
#pragma unroll
  for (int s = 1; s < 64; s <<= 1) d += __shfl_xor(d, s);

  if (lane == 0) {
    float z = d * INV_T;
    // logsig(z) = min(z,0) - log1p(exp(-|z|)) = logsig_neg(-z)
    float align   = logsig_neg(-z);
    float uniform = rowsum[n] * (1.0f / (float)M_);
    out[n]          = align + NEG_W * uniform;
    out[N_ + n]     = align;
    out[2 * N_ + n] = uniform;
  }
}

extern "C" void kernel_launch(void* const* d_in, const int* in_sizes, int n_in,
                              void* d_out, int out_size, void* d_ws,
                              size_t ws_size, hipStream_t stream) {
  const float* ref = (const float*)d_in[0];
  const float* pos = (const float*)d_in[1];
  const float* neg = (const float*)d_in[2];
  float* out = (float*)d_out;
  float* rowsum = (float*)d_ws;

  hipMemsetAsync(rowsum, 0, N_ * sizeof(float), stream);

  dim3 grid((N_ / BM) * (M_ / BN));  // 4096
  nce_gemm<<<grid, 256, 0, stream>>>(ref, neg, rowsum);
  nce_combine<<<N_ / 4, 256, 0, stream>>>(ref, pos, rowsum, out);
}

// Round 2
// 108.482 us; speedup vs baseline: 2.2990x; 2.2990x over previous
//
#include <hip/hip_runtime.h>

// NCE loss: out0 = align + w*uniform, out1 = align, out2 = uniform
// align[n]   = logsig(ref[n]·pos[n]/T)
// uniform[n] = mean_m logsig(-ref[n]·neg[m]/T)
// N=M=8192, D=512, T=0.5, w=1.0

typedef __attribute__((ext_vector_type(8))) short short8;
typedef __attribute__((ext_vector_type(8))) unsigned short ushort8;
typedef __attribute__((ext_vector_type(4))) float f32x4;

constexpr int N_ = 8192;
constexpr int M_ = 8192;
constexpr int D_ = 512;
constexpr float INV_T = 2.0f;
constexpr float NEG_W = 1.0f;
constexpr float LOG2E = 1.4426950408889634f;
constexpr float LN2   = 0.6931471805599453f;

#define BM 128
#define BN 128
#define BK 64
#define NKT (D_ / BK)  // 8

__device__ __forceinline__ unsigned short f2bf(float f) {
  unsigned int u = __builtin_bit_cast(unsigned int, f);
  u += 0x7FFFu + ((u >> 16) & 1u);  // RNE
  return (unsigned short)(u >> 16);
}

__device__ __forceinline__ float logsig_neg(float s) {
  // log sigmoid(-s) = min(-s,0) - log1p(exp(-|s|))
  float t = __builtin_fabsf(s);
  float e = __builtin_amdgcn_exp2f(-t * LOG2E);
  float l = __builtin_amdgcn_logf(1.0f + e) * LN2;
  return fminf(-s, 0.0f) - l;
}

// fp32 -> bf16, with the intra-row 16B-chunk XOR permutation pre-applied so
// that linear global_load_lds staging produces a bank-conflict-free swizzled
// LDS tile (rule #21: inverse-swizzled source + swizzled read).
__global__ __launch_bounds__(256) void cvt_pack(
    const float* __restrict__ refp, const float* __restrict__ negp,
    unsigned short* __restrict__ abf, unsigned short* __restrict__ bbf) {
  const int b = blockIdx.x;
  const float* src = (b < 2048) ? refp : negp;
  unsigned short* dst = (b < 2048) ? abf : bbf;
  const int i = (b & 2047) * 256 + threadIdx.x;  // 16B-group index
  const f32x4* s = reinterpret_cast<const f32x4*>(src) + (size_t)i * 2;
  f32x4 v0 = s[0], v1 = s[1];
  ushort8 o;
#pragma unroll
  for (int j = 0; j < 4; ++j) {
    o[j]     = f2bf(v0[j]);
    o[4 + j] = f2bf(v1[j]);
  }
  const unsigned int row = (unsigned int)i >> 6;   // 64 groups per 512-elem row
  const unsigned int seg = ((unsigned int)i >> 3) & 7;  // 128B K-segment
  const unsigned int c   = (unsigned int)i & 7;         // 16B chunk in segment
  const size_t byte =
      (size_t)row * 1024 + seg * 128 + (size_t)((c ^ (row & 7u)) << 4);
  *reinterpret_cast<ushort8*>(reinterpret_cast<char*>(dst) + byte) = o;
}

__global__ __launch_bounds__(256) void nce_gemm(
    const unsigned short* __restrict__ A,  // ref bf16 (pre-swizzled rows)
    const unsigned short* __restrict__ B,  // neg bf16 (pre-swizzled rows)
    float* __restrict__ rowsum) {          // (N,) fp32, pre-zeroed
  __shared__ __align__(16) unsigned short As[2][BM * BK];
  __shared__ __align__(16) unsigned short Bs[2][BN * BK];

  const int tid  = threadIdx.x;
  const int lane = tid & 63;
  const int wid  = tid >> 6;
  const int wr   = wid >> 1;
  const int wc   = wid & 1;

  // XCD-aware: 8-row band per XCD, column-major within the band
  // (B-tile reused 8x back-to-back; 1MB A-band stays L2-resident)
  const int bid = blockIdx.x;
  const int x   = bid & 7;    // xcd
  const int t   = bid >> 3;   // 0..511 within xcd
  const int brow = (x * 8 + (t & 7)) * BM;
  const int bcol = (t >> 3) * BN;

  // staging: each wave stages 32 rows of A and B per K-tile, 8 rows/call
  const int lr  = lane >> 3;         // 0..7
  const int lcb = (lane & 7) * 16;   // byte within 128B segment
  const char* gA =
      reinterpret_cast<const char*>(A) + (size_t)(brow + lr) * 1024 + lcb;
  const char* gB =
      reinterpret_cast<const char*>(B) + (size_t)(bcol + lr) * 1024 + lcb;

  f32x4 acc[4][4] = {};

#define STAGE(kt, buf)                                                        \
  {                                                                           \
    _Pragma("unroll") for (int j = 0; j < 4; ++j) {                           \
      const int rbase = wid * 32 + j * 8;                                     \
      __builtin_amdgcn_global_load_lds(                                       \
          (const __attribute__((address_space(1))) unsigned int*)(            \
              gA + (size_t)rbase * 1024 + (kt) * 128),                        \
          (__attribute__((address_space(3))) unsigned int*)(                  \
              &As[buf][rbase * 64]),                                          \
          16, 0, 0);                                                          \
      __builtin_amdgcn_global_load_lds(                                       \
          (const __attribute__((address_space(1))) unsigned int*)(            \
              gB + (size_t)rbase * 1024 + (kt) * 128),                        \
          (__attribute__((address_space(3))) unsigned int*)(                  \
              &Bs[buf][rbase * 64]),                                          \
          16, 0, 0);                                                          \
    }                                                                         \
  }

  STAGE(0, 0);
  __syncthreads();  // drains vmcnt(0) before s_barrier

  int cur = 0;
  for (int kt = 0; kt < NKT; ++kt) {
    if (kt + 1 < NKT) STAGE(kt + 1, cur ^ 1);  // prefetch overlaps MFMA

#pragma unroll
    for (int ks = 0; ks < 2; ++ks) {
      short8 af[4], bfr[4];
      const unsigned int kk2 = (unsigned int)(ks * 32 + (lane >> 4) * 8) * 2;
#pragma unroll
      for (int mf = 0; mf < 4; ++mf) {
        unsigned int row = wr * 64 + mf * 16 + (lane & 15);
        unsigned int off = row * 128u + (kk2 ^ ((row & 7u) << 4));
        af[mf] = *reinterpret_cast<const short8*>(
            reinterpret_cast<const char*>(As[cur]) + off);
      }
#pragma unroll
      for (int nf = 0; nf < 4; ++nf) {
        unsigned int row = wc * 64 + nf * 16 + (lane & 15);
        unsigned int off = row * 128u + (kk2 ^ ((row & 7u) << 4));
        bfr[nf] = *reinterpret_cast<const short8*>(
            reinterpret_cast<const char*>(Bs[cur]) + off);
      }
#pragma unroll
      for (int mf = 0; mf < 4; ++mf)
#pragma unroll
        for (int nf = 0; nf < 4; ++nf)
          acc[mf][nf] = __builtin_amdgcn_mfma_f32_16x16x32_bf16(
              af[mf], bfr[nf], acc[mf][nf], 0, 0, 0);
    }
    __syncthreads();  // drains vmcnt (staged tile ready) + LDS reads done
    cur ^= 1;
  }

  // epilogue: logsig(-s), reduce 128 cols of this tile, atomic per row
  float part[16];
#pragma unroll
  for (int mf = 0; mf < 4; ++mf)
#pragma unroll
    for (int r = 0; r < 4; ++r) {
      float ssum = 0.0f;
#pragma unroll
      for (int nf = 0; nf < 4; ++nf) {
        float s = acc[mf][nf][r] * INV_T;
        ssum += logsig_neg(s);
      }
      part[mf * 4 + r] = ssum;
    }
#pragma unroll
  for (int i = 0; i < 16; ++i) {
    float v = part[i];
    v += __shfl_xor(v, 1);
    v += __shfl_xor(v, 2);
    v += __shfl_xor(v, 4);
    v += __shfl_xor(v, 8);
    part[i] = v;
  }
  if ((lane & 15) == 0) {
    const int g = lane >> 4;
#pragma unroll
    for (int mf = 0; mf < 4; ++mf)
#pragma unroll
      for (int r = 0; r < 4; ++r)
        atomicAdd(&rowsum[brow + wr * 64 + mf * 16 + g * 4 + r],
                  part[mf * 4 + r]);
  }
}

__global__ __launch_bounds__(256) void nce_combine(
    const float* __restrict__ ref, const float* __restrict__ pos,
    const float* __restrict__ rowsum, float* __restrict__ out) {
  const int wid  = threadIdx.x >> 6;
  const int lane = threadIdx.x & 63;
  const int n    = blockIdx.x * 4 + wid;

  const f32x4* pr =
      reinterpret_cast<const f32x4*>(ref + (size_t)n * D_ + lane * 8);
  const f32x4* pp =
      reinterpret_cast<const f32x4*>(pos + (size_t)n * D_ + lane * 8);
  f32x4 a0 = pr[0], a1 = pr[1], b0 = pp[0], b1 = pp[1];
  float d = 0.0f;
#pragma unroll
  for (int i = 0; i < 4; ++i) d = __builtin_fmaf(a0[i], b0[i], d);
#pragma unroll
  for (int i = 0; i < 4; ++i) d = __builtin_fmaf(a1[i], b1[i], d);
#pragma unroll
  for (int s = 1; s < 64; s <<= 1) d += __shfl_xor(d, s);

  if (lane == 0) {
    float z = d * INV_T;
    float align   = logsig_neg(-z);
    float uniform = rowsum[n] * (1.0f / (float)M_);
    out[n]          = align + NEG_W * uniform;
    out[N_ + n]     = align;
    out[2 * N_ + n] = uniform;
  }
}

extern "C" void kernel_launch(void* const* d_in, const int* in_sizes, int n_in,
                              void* d_out, int out_size, void* d_ws,
                              size_t ws_size, hipStream_t stream) {
  const float* ref = (const float*)d_in[0];
  const float* pos = (const float*)d_in[1];
  const float* neg = (const float*)d_in[2];
  float* out = (float*)d_out;

  float* rowsum = (float*)d_ws;                                // 32 KB
  unsigned short* abf = (unsigned short*)((char*)d_ws + 32768);  // 8 MB
  unsigned short* bbf = abf + (size_t)N_ * D_;                   // 8 MB

  hipMemsetAsync(rowsum, 0, N_ * sizeof(float), stream);
  cvt_pack<<<4096, 256, 0, stream>>>(ref, neg, abf, bbf);
  nce_gemm<<<4096, 256, 0, stream>>>(abf, bbf, rowsum);
  nce_combine<<<N_ / 4, 256, 0, stream>>>(ref, pos, rowsum, out);
}